// Round 1
// baseline (930.489 us; speedup 1.0000x reference)
//
#include <hip/hip_runtime.h>
#include <stdint.h>

// ---------------------------------------------------------------------------
// UnimpNet: h = x + mask*emb[y]; q/k/v/skip = h@W*+b; per-edge softmax attn
// (scatter over dst); out = (agg + skip) @ Wout + bout.
// N=100000, E=3200000, F=256, HEADS=2, C=8 (HC=16), NUM_CLASSES=40.
// ---------------------------------------------------------------------------

constexpr int F_DIM = 256;
constexpr int HC = 16;      // HEADS*C
constexpr int NC = 40;      // num classes
constexpr float RSQRT8 = 0.35355339059327373f;

__device__ __forceinline__ unsigned int bfbits(float f) {
  unsigned int u = __float_as_uint(f);
  return (u + 0x7fffu + ((u >> 16) & 1u)) >> 16;   // RNE f32->bf16 bits
}
__device__ __forceinline__ float bflo(unsigned int u) { return __uint_as_float(u << 16); }
__device__ __forceinline__ float bfhi(unsigned int u) { return __uint_as_float(u & 0xffff0000u); }

// --------------------------- mask layout detect ----------------------------
// label_mask is jax bool -> most likely 1 byte/elem; could be int32. Detect:
// if bytes 1..3 of the first 1024 int32 slots are all zero => int32 layout.
__global__ void detect_mask_kernel(const unsigned char* __restrict__ m, int* __restrict__ flag) {
  __shared__ int any;
  if (threadIdx.x == 0) any = 0;
  __syncthreads();
  int acc = 0;
  for (int i = threadIdx.x; i < 1024; i += blockDim.x)
    acc |= m[i * 4 + 1] | m[i * 4 + 2] | m[i * 4 + 3];
  if (acc) atomicOr(&any, 1);
  __syncthreads();
  if (threadIdx.x == 0) *flag = any ? 0 : 1;   // 1 == int32 layout
}

// --------------------- fused maskemb + 4 GEMMs (q,k,v,skip) ----------------
// Block = 256 threads = 256 nodes. x staged via LDS in 32-feature chunks.
// Weights are wave-uniform -> scalar loads; 64 accumulators per thread.
constexpr int NPB = 256;
constexpr int CHUNK = 32;

__global__ __launch_bounds__(256) void fused_gemm_kernel(
    const float* __restrict__ x, const int* __restrict__ y,
    const unsigned char* __restrict__ maskraw, const int* __restrict__ flag,
    const float* __restrict__ emb,
    const float* __restrict__ Wq, const float* __restrict__ bq,
    const float* __restrict__ Wk, const float* __restrict__ bk,
    const float* __restrict__ Wv, const float* __restrict__ bv,
    const float* __restrict__ Ws, const float* __restrict__ bs,
    float* __restrict__ qout, float* __restrict__ skipout,
    unsigned int* __restrict__ kvout, int n)
{
  __shared__ float tile[NPB][CHUNK + 1];
  const int tid = threadIdx.x;
  const int nb = blockIdx.x * NPB;
  const int flg = *flag;

  float accq[16], acck[16], accv[16], accs[16];
#pragma unroll
  for (int o = 0; o < 16; ++o) { accq[o] = 0.f; acck[o] = 0.f; accv[o] = 0.f; accs[o] = 0.f; }

  const float4* x4 = (const float4*)x;
  const float4* emb4 = (const float4*)emb;
  const int* mask_i = (const int*)maskraw;

  for (int c = 0; c < F_DIM / CHUNK; ++c) {
    // stage 256 nodes x 32 features (as float4), fusing the label-emb add
#pragma unroll
    for (int it = 0; it < 8; ++it) {
      int idx = tid + it * 256;
      int node = idx >> 3;
      int j = idx & 7;
      int gn = nb + node;
      float4 v = make_float4(0.f, 0.f, 0.f, 0.f);
      if (gn < n) {
        v = x4[(size_t)gn * (F_DIM / 4) + c * 8 + j];
        bool msk = flg ? (mask_i[gn] != 0) : (maskraw[gn] != 0);
        if (msk) {
          int cls = y[gn];
          float4 e = emb4[(size_t)cls * (F_DIM / 4) + c * 8 + j];
          v.x += e.x; v.y += e.y; v.z += e.z; v.w += e.w;
        }
      }
      tile[node][j * 4 + 0] = v.x;
      tile[node][j * 4 + 1] = v.y;
      tile[node][j * 4 + 2] = v.z;
      tile[node][j * 4 + 3] = v.w;
    }
    __syncthreads();
    for (int fj = 0; fj < CHUNK; ++fj) {
      float hf = tile[tid][fj];
      int fb = (c * CHUNK + fj) * 16;
#pragma unroll
      for (int o = 0; o < 16; ++o) accq[o] = fmaf(hf, Wq[fb + o], accq[o]);
#pragma unroll
      for (int o = 0; o < 16; ++o) acck[o] = fmaf(hf, Wk[fb + o], acck[o]);
#pragma unroll
      for (int o = 0; o < 16; ++o) accv[o] = fmaf(hf, Wv[fb + o], accv[o]);
#pragma unroll
      for (int o = 0; o < 16; ++o) accs[o] = fmaf(hf, Ws[fb + o], accs[o]);
    }
    __syncthreads();
  }

  int node = nb + tid;
  if (node < n) {
    // q is pre-scaled by 1/sqrt(C) so the edge kernel does a plain dot.
    float4* q4 = (float4*)(qout + (size_t)node * 16);
    float4* s4 = (float4*)(skipout + (size_t)node * 16);
#pragma unroll
    for (int j = 0; j < 4; ++j) {
      q4[j] = make_float4((accq[4 * j + 0] + bq[4 * j + 0]) * RSQRT8,
                          (accq[4 * j + 1] + bq[4 * j + 1]) * RSQRT8,
                          (accq[4 * j + 2] + bq[4 * j + 2]) * RSQRT8,
                          (accq[4 * j + 3] + bq[4 * j + 3]) * RSQRT8);
      s4[j] = make_float4(accs[4 * j + 0] + bs[4 * j + 0],
                          accs[4 * j + 1] + bs[4 * j + 1],
                          accs[4 * j + 2] + bs[4 * j + 2],
                          accs[4 * j + 3] + bs[4 * j + 3]);
    }
    // kv packed bf16: k[0..15], v[0..15] -> 16 uints
    unsigned int kvw[8];
#pragma unroll
    for (int j = 0; j < 8; ++j)
      kvw[j] = bfbits(acck[2 * j] + bk[2 * j]) | (bfbits(acck[2 * j + 1] + bk[2 * j + 1]) << 16);
    uint4* kvp = (uint4*)(kvout + (size_t)node * 16);
    kvp[0] = make_uint4(kvw[0], kvw[1], kvw[2], kvw[3]);
    kvp[1] = make_uint4(kvw[4], kvw[5], kvw[6], kvw[7]);
#pragma unroll
    for (int j = 0; j < 8; ++j)
      kvw[j] = bfbits(accv[2 * j] + bv[2 * j]) | (bfbits(accv[2 * j + 1] + bv[2 * j + 1]) << 16);
    kvp[2] = make_uint4(kvw[0], kvw[1], kvw[2], kvw[3]);
    kvp[3] = make_uint4(kvw[4], kvw[5], kvw[6], kvw[7]);
  }
}

// ------------------------------ histogram ----------------------------------
__global__ void hist_kernel(const int* __restrict__ dst, int* __restrict__ counts, int etot) {
  int stride = gridDim.x * blockDim.x;
  for (int e = blockIdx.x * blockDim.x + threadIdx.x; e < etot; e += stride)
    atomicAdd(&counts[dst[e]], 1);
}

// ----------------- block scan + atomic base (CSR offsets) ------------------
// Segment base order across blocks is arbitrary (atomic arrival) -- harmless.
__global__ __launch_bounds__(1024) void scan_kernel(
    const int* __restrict__ counts, int* __restrict__ offsets,
    int* __restrict__ cursor, int* __restrict__ gc, int n)
{
  __shared__ int s[1024];
  __shared__ int base_sh;
  int tid = threadIdx.x;
  int i = blockIdx.x * 1024 + tid;
  int v = (i < n) ? counts[i] : 0;
  s[tid] = v;
  __syncthreads();
  for (int offd = 1; offd < 1024; offd <<= 1) {
    int t = (tid >= offd) ? s[tid - offd] : 0;
    __syncthreads();
    s[tid] += t;
    __syncthreads();
  }
  if (tid == 1023) base_sh = atomicAdd(gc, s[1023]);
  __syncthreads();
  int excl = s[tid] - v + base_sh;
  if (i < n) { offsets[i] = excl; cursor[i] = excl; }
}

// ------------------------------ CSR scatter --------------------------------
__global__ void scatter_kernel(const int* __restrict__ srcA, const int* __restrict__ dstA,
                               int* __restrict__ cursor, int* __restrict__ csr, int etot) {
  int stride = gridDim.x * blockDim.x;
  for (int e = blockIdx.x * blockDim.x + threadIdx.x; e < etot; e += stride) {
    int d = dstA[e];
    int pos = atomicAdd(&cursor[d], 1);
    csr[pos] = srcA[e];
  }
}

// ------------- per-dst attention softmax + agg + classifier ----------------
// One wave per dst node. exp is computed without the max-shift (it cancels;
// |alpha| <~ 5 so no overflow risk). Fuses skip-add and the 16x40 classifier.
__global__ __launch_bounds__(256) void edge_attn_kernel(
    const int* __restrict__ csr, const int* __restrict__ offsets,
    const int* __restrict__ counts, const float* __restrict__ q,
    const float* __restrict__ skip, const unsigned int* __restrict__ kv,
    const float* __restrict__ Wout, const float* __restrict__ bout,
    float* __restrict__ out, int n)
{
  int wave = (blockIdx.x * blockDim.x + threadIdx.x) >> 6;
  int lane = threadIdx.x & 63;
  if (wave >= n) return;
  int dst = __builtin_amdgcn_readfirstlane(wave);

  int start = offsets[dst];
  int cnt = counts[dst];

  float qv[16];
#pragma unroll
  for (int o = 0; o < 16; ++o) qv[o] = q[(size_t)dst * 16 + o];

  float es0 = 0.f, es1 = 0.f;
  float acc[16];
#pragma unroll
  for (int o = 0; o < 16; ++o) acc[o] = 0.f;

  for (int b = 0; b < cnt; b += 64) {
    int e = b + lane;
    if (e < cnt) {
      int s = csr[start + e];
      const uint4* kvp = (const uint4*)(kv + (size_t)s * 16);
      uint4 kA = kvp[0], kB = kvp[1], vA = kvp[2], vB = kvp[3];
      float kf[16], vf[16];
      kf[0] = bflo(kA.x); kf[1] = bfhi(kA.x); kf[2] = bflo(kA.y); kf[3] = bfhi(kA.y);
      kf[4] = bflo(kA.z); kf[5] = bfhi(kA.z); kf[6] = bflo(kA.w); kf[7] = bfhi(kA.w);
      kf[8] = bflo(kB.x); kf[9] = bfhi(kB.x); kf[10] = bflo(kB.y); kf[11] = bfhi(kB.y);
      kf[12] = bflo(kB.z); kf[13] = bfhi(kB.z); kf[14] = bflo(kB.w); kf[15] = bfhi(kB.w);
      vf[0] = bflo(vA.x); vf[1] = bfhi(vA.x); vf[2] = bflo(vA.y); vf[3] = bfhi(vA.y);
      vf[4] = bflo(vA.z); vf[5] = bfhi(vA.z); vf[6] = bflo(vA.w); vf[7] = bfhi(vA.w);
      vf[8] = bflo(vB.x); vf[9] = bfhi(vB.x); vf[10] = bflo(vB.y); vf[11] = bfhi(vB.y);
      vf[12] = bflo(vB.z); vf[13] = bfhi(vB.z); vf[14] = bflo(vB.w); vf[15] = bfhi(vB.w);
      float a0 = 0.f, a1 = 0.f;
#pragma unroll
      for (int c2 = 0; c2 < 8; ++c2) {
        a0 = fmaf(qv[c2], kf[c2], a0);
        a1 = fmaf(qv[8 + c2], kf[8 + c2], a1);
      }
      float e0 = __expf(a0), e1 = __expf(a1);
      es0 += e0; es1 += e1;
#pragma unroll
      for (int c2 = 0; c2 < 8; ++c2) {
        acc[c2] = fmaf(e0, vf[c2], acc[c2]);
        acc[8 + c2] = fmaf(e1, vf[8 + c2], acc[8 + c2]);
      }
    }
  }

#pragma unroll
  for (int m = 1; m <= 32; m <<= 1) {
    es0 += __shfl_xor(es0, m, 64);
    es1 += __shfl_xor(es1, m, 64);
#pragma unroll
    for (int o = 0; o < 16; ++o) acc[o] += __shfl_xor(acc[o], m, 64);
  }

  float d0 = es0 + 1e-16f, d1 = es1 + 1e-16f;
  float out16[16];
#pragma unroll
  for (int o = 0; o < 8; ++o)  out16[o] = acc[o] / d0 + skip[(size_t)dst * 16 + o];
#pragma unroll
  for (int o = 8; o < 16; ++o) out16[o] = acc[o] / d1 + skip[(size_t)dst * 16 + o];

  if (lane < NC) {
    float r = bout[lane];
#pragma unroll
    for (int c2 = 0; c2 < 16; ++c2) r = fmaf(out16[c2], Wout[c2 * NC + lane], r);
    out[(size_t)dst * NC + lane] = r;
  }
}

// ---------------------------------------------------------------------------
extern "C" void kernel_launch(void* const* d_in, const int* in_sizes, int n_in,
                              void* d_out, int out_size, void* d_ws, size_t ws_size,
                              hipStream_t stream) {
  const float* x = (const float*)d_in[0];
  const int* y = (const int*)d_in[1];
  const int* ei = (const int*)d_in[2];
  const unsigned char* mask = (const unsigned char*)d_in[3];
  const float* emb = (const float*)d_in[4];
  const float* Wq = (const float*)d_in[5];
  const float* bq = (const float*)d_in[6];
  const float* Wk = (const float*)d_in[7];
  const float* bk = (const float*)d_in[8];
  const float* Wv = (const float*)d_in[9];
  const float* bv = (const float*)d_in[10];
  const float* Ws = (const float*)d_in[11];
  const float* bs = (const float*)d_in[12];
  const float* Wout = (const float*)d_in[13];
  const float* bout = (const float*)d_in[14];

  const int n = in_sizes[1];          // 100000
  const int etot = in_sizes[2] / 2;   // 3200000

  char* w = (char*)d_ws;
  size_t off = 0;
  auto alloc = [&](size_t bytes) -> void* {
    off = (off + 255) & ~(size_t)255;
    void* p = w + off;
    off += bytes;
    return p;
  };
  int* flag = (int*)alloc(sizeof(int));
  float* qbuf = (float*)alloc((size_t)n * 16 * sizeof(float));
  float* skipbuf = (float*)alloc((size_t)n * 16 * sizeof(float));
  unsigned int* kvbuf = (unsigned int*)alloc((size_t)n * 16 * sizeof(unsigned int));
  int* counts = (int*)alloc(((size_t)n + 1) * sizeof(int));   // +1 = global cursor
  int* gc = counts + n;
  int* offsets = (int*)alloc((size_t)n * sizeof(int));
  int* cursor = (int*)alloc((size_t)n * sizeof(int));
  int* csr = (int*)alloc((size_t)etot * sizeof(int));

  hipMemsetAsync(counts, 0, ((size_t)n + 1) * sizeof(int), stream);
  detect_mask_kernel<<<1, 256, 0, stream>>>(mask, flag);
  fused_gemm_kernel<<<(n + NPB - 1) / NPB, 256, 0, stream>>>(
      x, y, mask, flag, emb, Wq, bq, Wk, bk, Wv, bv, Ws, bs,
      qbuf, skipbuf, kvbuf, n);
  hist_kernel<<<2048, 256, 0, stream>>>(ei + etot, counts, etot);
  scan_kernel<<<(n + 1023) / 1024, 1024, 0, stream>>>(counts, offsets, cursor, gc, n);
  scatter_kernel<<<2048, 256, 0, stream>>>(ei, ei + etot, cursor, csr, etot);
  edge_attn_kernel<<<(n + 3) / 4, 256, 0, stream>>>(
      csr, offsets, counts, qbuf, skipbuf, kvbuf, Wout, bout, (float*)d_out, n);
}

// Round 2
// 781.275 us; speedup vs baseline: 1.1910x; 1.1910x over previous
//
#include <hip/hip_runtime.h>
#include <stdint.h>

// ---------------------------------------------------------------------------
// UnimpNet: h = x + mask*emb[y]; q/k/v/skip = h@W*+b; per-edge softmax attn
// (scatter over dst); out = (agg + skip) @ Wout + bout.
// N=100000, E=3200000, F=256, HEADS=2, C=8 (HC=16), NUM_CLASSES=40.
//
// CSR build is a two-level bucket sort (LDS atomics only, L2-local writes):
//   A) per-block LDS hist of dst>>9 buckets -> M[block][bucket]
//   B) scan M -> per-block bases + bucket bases
//   C) scatter packed (dstlow,src) into bucket regions via LDS cursors
//   D) per-bucket: LDS-stage edges, 512-ctr hist, scan, in-place CSR scatter
// ---------------------------------------------------------------------------

constexpr int F_DIM = 256;
constexpr int NC = 40;      // num classes
constexpr float RSQRT8 = 0.35355339059327373f;

constexpr int SHIFT = 9;            // nodes per bucket = 512 (n <= 131072)
constexpr int NPBKT = 1 << SHIFT;   // 512
constexpr int NBLK1 = 512;          // blocks for hist/scatter passes
constexpr int MAXB1 = 256;          // max buckets (LDS arrays)
constexpr int DCAP = 32768;         // per-bucket LDS edge staging cap (128KB)

__device__ __forceinline__ unsigned int bfbits(float f) {
  unsigned int u = __float_as_uint(f);
  return (u + 0x7fffu + ((u >> 16) & 1u)) >> 16;   // RNE f32->bf16 bits
}
__device__ __forceinline__ float bflo(unsigned int u) { return __uint_as_float(u << 16); }
__device__ __forceinline__ float bfhi(unsigned int u) { return __uint_as_float(u & 0xffff0000u); }

// --------------------------- mask layout detect ----------------------------
__global__ void detect_mask_kernel(const unsigned char* __restrict__ m, int* __restrict__ flag) {
  __shared__ int any;
  if (threadIdx.x == 0) any = 0;
  __syncthreads();
  int acc = 0;
  for (int i = threadIdx.x; i < 1024; i += blockDim.x)
    acc |= m[i * 4 + 1] | m[i * 4 + 2] | m[i * 4 + 3];
  if (acc) atomicOr(&any, 1);
  __syncthreads();
  if (threadIdx.x == 0) *flag = any ? 0 : 1;   // 1 == int32 layout
}

// --------------------- fused maskemb + 4 GEMMs (q,k,v,skip) ----------------
constexpr int NPB = 256;
constexpr int CHUNK = 32;

__global__ __launch_bounds__(256) void fused_gemm_kernel(
    const float* __restrict__ x, const int* __restrict__ y,
    const unsigned char* __restrict__ maskraw, const int* __restrict__ flag,
    const float* __restrict__ emb,
    const float* __restrict__ Wq, const float* __restrict__ bq,
    const float* __restrict__ Wk, const float* __restrict__ bk,
    const float* __restrict__ Wv, const float* __restrict__ bv,
    const float* __restrict__ Ws, const float* __restrict__ bs,
    float* __restrict__ qout, float* __restrict__ skipout,
    unsigned int* __restrict__ kvout, int n)
{
  __shared__ float tile[NPB][CHUNK + 1];
  const int tid = threadIdx.x;
  const int nb = blockIdx.x * NPB;
  const int flg = *flag;

  float accq[16], acck[16], accv[16], accs[16];
#pragma unroll
  for (int o = 0; o < 16; ++o) { accq[o] = 0.f; acck[o] = 0.f; accv[o] = 0.f; accs[o] = 0.f; }

  const float4* x4 = (const float4*)x;
  const float4* emb4 = (const float4*)emb;
  const int* mask_i = (const int*)maskraw;

  for (int c = 0; c < F_DIM / CHUNK; ++c) {
#pragma unroll
    for (int it = 0; it < 8; ++it) {
      int idx = tid + it * 256;
      int node = idx >> 3;
      int j = idx & 7;
      int gn = nb + node;
      float4 v = make_float4(0.f, 0.f, 0.f, 0.f);
      if (gn < n) {
        v = x4[(size_t)gn * (F_DIM / 4) + c * 8 + j];
        bool msk = flg ? (mask_i[gn] != 0) : (maskraw[gn] != 0);
        if (msk) {
          int cls = y[gn];
          float4 e = emb4[(size_t)cls * (F_DIM / 4) + c * 8 + j];
          v.x += e.x; v.y += e.y; v.z += e.z; v.w += e.w;
        }
      }
      tile[node][j * 4 + 0] = v.x;
      tile[node][j * 4 + 1] = v.y;
      tile[node][j * 4 + 2] = v.z;
      tile[node][j * 4 + 3] = v.w;
    }
    __syncthreads();
    for (int fj = 0; fj < CHUNK; ++fj) {
      float hf = tile[tid][fj];
      int fb = (c * CHUNK + fj) * 16;
#pragma unroll
      for (int o = 0; o < 16; ++o) accq[o] = fmaf(hf, Wq[fb + o], accq[o]);
#pragma unroll
      for (int o = 0; o < 16; ++o) acck[o] = fmaf(hf, Wk[fb + o], acck[o]);
#pragma unroll
      for (int o = 0; o < 16; ++o) accv[o] = fmaf(hf, Wv[fb + o], accv[o]);
#pragma unroll
      for (int o = 0; o < 16; ++o) accs[o] = fmaf(hf, Ws[fb + o], accs[o]);
    }
    __syncthreads();
  }

  int node = nb + tid;
  if (node < n) {
    float4* q4 = (float4*)(qout + (size_t)node * 16);
    float4* s4 = (float4*)(skipout + (size_t)node * 16);
#pragma unroll
    for (int j = 0; j < 4; ++j) {
      q4[j] = make_float4((accq[4 * j + 0] + bq[4 * j + 0]) * RSQRT8,
                          (accq[4 * j + 1] + bq[4 * j + 1]) * RSQRT8,
                          (accq[4 * j + 2] + bq[4 * j + 2]) * RSQRT8,
                          (accq[4 * j + 3] + bq[4 * j + 3]) * RSQRT8);
      s4[j] = make_float4(accs[4 * j + 0] + bs[4 * j + 0],
                          accs[4 * j + 1] + bs[4 * j + 1],
                          accs[4 * j + 2] + bs[4 * j + 2],
                          accs[4 * j + 3] + bs[4 * j + 3]);
    }
    unsigned int kvw[8];
#pragma unroll
    for (int j = 0; j < 8; ++j)
      kvw[j] = bfbits(acck[2 * j] + bk[2 * j]) | (bfbits(acck[2 * j + 1] + bk[2 * j + 1]) << 16);
    uint4* kvp = (uint4*)(kvout + (size_t)node * 16);
    kvp[0] = make_uint4(kvw[0], kvw[1], kvw[2], kvw[3]);
    kvp[1] = make_uint4(kvw[4], kvw[5], kvw[6], kvw[7]);
#pragma unroll
    for (int j = 0; j < 8; ++j)
      kvw[j] = bfbits(accv[2 * j] + bv[2 * j]) | (bfbits(accv[2 * j + 1] + bv[2 * j + 1]) << 16);
    kvp[2] = make_uint4(kvw[0], kvw[1], kvw[2], kvw[3]);
    kvp[3] = make_uint4(kvw[4], kvw[5], kvw[6], kvw[7]);
  }
}

// ------------------ A) per-block bucket histogram (LDS only) ---------------
__global__ __launch_bounds__(256) void bucket_hist_kernel(
    const int* __restrict__ dstA, int* __restrict__ M, int etot, int chunk, int nb1)
{
  __shared__ int h[MAXB1];
  const int tid = threadIdx.x, b = blockIdx.x;
  for (int i = tid; i < nb1; i += 256) h[i] = 0;
  __syncthreads();
  int s = b * chunk, e = min(etot, s + chunk);
  for (int i = s + tid; i < e; i += 256) atomicAdd(&h[dstA[i] >> SHIFT], 1);
  __syncthreads();
  for (int i = tid; i < nb1; i += 256) M[b * nb1 + i] = h[i];
}

// ------------------ B) scan: bucket bases + per-block bases ---------------
__global__ __launch_bounds__(256) void bucket_scan_kernel(
    int* __restrict__ M, int* __restrict__ bucket_base, int nblk, int nb1, int etot)
{
  __shared__ int tot[MAXB1], sc[MAXB1];
  const int k = threadIdx.x;
  int t = 0;
  if (k < nb1) for (int b = 0; b < nblk; ++b) t += M[b * nb1 + k];
  tot[k] = (k < nb1) ? t : 0;
  __syncthreads();
  sc[k] = tot[k];
  __syncthreads();
  for (int off = 1; off < MAXB1; off <<= 1) {
    int tt = (k >= off) ? sc[k - off] : 0;
    __syncthreads();
    sc[k] += tt;
    __syncthreads();
  }
  if (k < nb1) {
    int base = sc[k] - tot[k];
    bucket_base[k] = base;
    int run = base;
    for (int b = 0; b < nblk; ++b) { int m = M[b * nb1 + k]; M[b * nb1 + k] = run; run += m; }
  }
  if (k == 0) bucket_base[nb1] = etot;
}

// ------------------ C) scatter packed edges into bucket regions ------------
__global__ __launch_bounds__(256) void bucket_scatter_kernel(
    const int* __restrict__ srcA, const int* __restrict__ dstA,
    const int* __restrict__ M, unsigned int* __restrict__ bucketed,
    int etot, int chunk, int nb1)
{
  __shared__ int c[MAXB1];
  const int tid = threadIdx.x, b = blockIdx.x;
  for (int i = tid; i < nb1; i += 256) c[i] = M[b * nb1 + i];
  __syncthreads();
  int s = b * chunk, e = min(etot, s + chunk);
  for (int i = s + tid; i < e; i += 256) {
    int d = dstA[i];
    int k = d >> SHIFT;
    int pos = atomicAdd(&c[k], 1);
    bucketed[pos] = ((unsigned)(d & (NPBKT - 1)) << 17) | (unsigned)srcA[i];
  }
}

// ------------- D) per-bucket CSR: stage in LDS, hist, scan, scatter --------
// In-place: all global reads of the bucket region finish (into LDS) before
// any global write to it. Final region content = src indices grouped by dst.
__global__ __launch_bounds__(1024) void csr_build_kernel(
    unsigned int* __restrict__ bucketed, const int* __restrict__ bucket_base,
    int* __restrict__ offsets, int* __restrict__ counts, int n)
{
  extern __shared__ unsigned int sedge[];          // DCAP entries
  __shared__ int h[NPBKT], sc[NPBKT], cur[NPBKT];
  const int tid = threadIdx.x, k = blockIdx.x;
  const int base = bucket_base[k];
  int cnt = bucket_base[k + 1] - base;
  if (cnt > DCAP) cnt = DCAP;                      // ~6-sigma safe; never hit
  if (tid < NPBKT) h[tid] = 0;
  __syncthreads();
  for (int i = tid; i < cnt; i += 1024) {
    unsigned p = bucketed[base + i];
    sedge[i] = p;
    atomicAdd(&h[p >> 17], 1);
  }
  __syncthreads();
  int v = (tid < NPBKT) ? h[tid] : 0;
  if (tid < NPBKT) sc[tid] = v;
  __syncthreads();
  for (int off = 1; off < NPBKT; off <<= 1) {
    int t = 0;
    if (tid < NPBKT && tid >= off) t = sc[tid - off];
    __syncthreads();
    if (tid < NPBKT) sc[tid] += t;
    __syncthreads();
  }
  if (tid < NPBKT) {
    int excl = sc[tid] - v;
    cur[tid] = excl;
    int node = (k << SHIFT) + tid;
    if (node < n) { offsets[node] = base + excl; counts[node] = v; }
  }
  __syncthreads();
  for (int i = tid; i < cnt; i += 1024) {
    unsigned p = sedge[i];
    int pos = atomicAdd(&cur[p >> 17], 1);
    bucketed[base + pos] = p & 0x1FFFFu;
  }
}

// ------------- per-dst attention softmax + agg + classifier ----------------
__global__ __launch_bounds__(256) void edge_attn_kernel(
    const int* __restrict__ csr, const int* __restrict__ offsets,
    const int* __restrict__ counts, const float* __restrict__ q,
    const float* __restrict__ skip, const unsigned int* __restrict__ kv,
    const float* __restrict__ Wout, const float* __restrict__ bout,
    float* __restrict__ out, int n)
{
  int wave = (blockIdx.x * blockDim.x + threadIdx.x) >> 6;
  int lane = threadIdx.x & 63;
  if (wave >= n) return;
  int dst = __builtin_amdgcn_readfirstlane(wave);

  int start = offsets[dst];
  int cnt = counts[dst];

  float qv[16];
#pragma unroll
  for (int o = 0; o < 16; ++o) qv[o] = q[(size_t)dst * 16 + o];

  float es0 = 0.f, es1 = 0.f;
  float acc[16];
#pragma unroll
  for (int o = 0; o < 16; ++o) acc[o] = 0.f;

  for (int b = 0; b < cnt; b += 64) {
    int e = b + lane;
    if (e < cnt) {
      int s = csr[start + e];
      const uint4* kvp = (const uint4*)(kv + (size_t)s * 16);
      uint4 kA = kvp[0], kB = kvp[1], vA = kvp[2], vB = kvp[3];
      float kf[16], vf[16];
      kf[0] = bflo(kA.x); kf[1] = bfhi(kA.x); kf[2] = bflo(kA.y); kf[3] = bfhi(kA.y);
      kf[4] = bflo(kA.z); kf[5] = bfhi(kA.z); kf[6] = bflo(kA.w); kf[7] = bfhi(kA.w);
      kf[8] = bflo(kB.x); kf[9] = bfhi(kB.x); kf[10] = bflo(kB.y); kf[11] = bfhi(kB.y);
      kf[12] = bflo(kB.z); kf[13] = bfhi(kB.z); kf[14] = bflo(kB.w); kf[15] = bfhi(kB.w);
      vf[0] = bflo(vA.x); vf[1] = bfhi(vA.x); vf[2] = bflo(vA.y); vf[3] = bfhi(vA.y);
      vf[4] = bflo(vA.z); vf[5] = bfhi(vA.z); vf[6] = bflo(vA.w); vf[7] = bfhi(vA.w);
      vf[8] = bflo(vB.x); vf[9] = bfhi(vB.x); vf[10] = bflo(vB.y); vf[11] = bfhi(vB.y);
      vf[12] = bflo(vB.z); vf[13] = bfhi(vB.z); vf[14] = bflo(vB.w); vf[15] = bfhi(vB.w);
      float a0 = 0.f, a1 = 0.f;
#pragma unroll
      for (int c2 = 0; c2 < 8; ++c2) {
        a0 = fmaf(qv[c2], kf[c2], a0);
        a1 = fmaf(qv[8 + c2], kf[8 + c2], a1);
      }
      float e0 = __expf(a0), e1 = __expf(a1);
      es0 += e0; es1 += e1;
#pragma unroll
      for (int c2 = 0; c2 < 8; ++c2) {
        acc[c2] = fmaf(e0, vf[c2], acc[c2]);
        acc[8 + c2] = fmaf(e1, vf[8 + c2], acc[8 + c2]);
      }
    }
  }

#pragma unroll
  for (int m = 1; m <= 32; m <<= 1) {
    es0 += __shfl_xor(es0, m, 64);
    es1 += __shfl_xor(es1, m, 64);
#pragma unroll
    for (int o = 0; o < 16; ++o) acc[o] += __shfl_xor(acc[o], m, 64);
  }

  float d0 = es0 + 1e-16f, d1 = es1 + 1e-16f;
  float out16[16];
#pragma unroll
  for (int o = 0; o < 8; ++o)  out16[o] = acc[o] / d0 + skip[(size_t)dst * 16 + o];
#pragma unroll
  for (int o = 8; o < 16; ++o) out16[o] = acc[o] / d1 + skip[(size_t)dst * 16 + o];

  if (lane < NC) {
    float r = bout[lane];
#pragma unroll
    for (int c2 = 0; c2 < 16; ++c2) r = fmaf(out16[c2], Wout[c2 * NC + lane], r);
    out[(size_t)dst * NC + lane] = r;
  }
}

// ---------------------------------------------------------------------------
extern "C" void kernel_launch(void* const* d_in, const int* in_sizes, int n_in,
                              void* d_out, int out_size, void* d_ws, size_t ws_size,
                              hipStream_t stream) {
  const float* x = (const float*)d_in[0];
  const int* y = (const int*)d_in[1];
  const int* ei = (const int*)d_in[2];
  const unsigned char* mask = (const unsigned char*)d_in[3];
  const float* emb = (const float*)d_in[4];
  const float* Wq = (const float*)d_in[5];
  const float* bq = (const float*)d_in[6];
  const float* Wk = (const float*)d_in[7];
  const float* bk = (const float*)d_in[8];
  const float* Wv = (const float*)d_in[9];
  const float* bv = (const float*)d_in[10];
  const float* Ws = (const float*)d_in[11];
  const float* bs = (const float*)d_in[12];
  const float* Wout = (const float*)d_in[13];
  const float* bout = (const float*)d_in[14];

  const int n = in_sizes[1];          // 100000
  const int etot = in_sizes[2] / 2;   // 3200000
  const int nb1 = (n + NPBKT - 1) >> SHIFT;          // 196 buckets
  const int chunk = (etot + NBLK1 - 1) / NBLK1;      // edges per block

  char* w = (char*)d_ws;
  size_t off = 0;
  auto alloc = [&](size_t bytes) -> void* {
    off = (off + 255) & ~(size_t)255;
    void* p = w + off;
    off += bytes;
    return p;
  };
  int* flag = (int*)alloc(sizeof(int));
  float* qbuf = (float*)alloc((size_t)n * 16 * sizeof(float));
  float* skipbuf = (float*)alloc((size_t)n * 16 * sizeof(float));
  unsigned int* kvbuf = (unsigned int*)alloc((size_t)n * 16 * sizeof(unsigned int));
  int* counts = (int*)alloc((size_t)n * sizeof(int));
  int* offsets = (int*)alloc((size_t)n * sizeof(int));
  int* M = (int*)alloc((size_t)NBLK1 * nb1 * sizeof(int));
  int* bucket_base = (int*)alloc(((size_t)nb1 + 1) * sizeof(int));
  unsigned int* bucketed = (unsigned int*)alloc((size_t)etot * sizeof(unsigned int));

  detect_mask_kernel<<<1, 256, 0, stream>>>(mask, flag);
  fused_gemm_kernel<<<(n + NPB - 1) / NPB, 256, 0, stream>>>(
      x, y, mask, flag, emb, Wq, bq, Wk, bk, Wv, bv, Ws, bs,
      qbuf, skipbuf, kvbuf, n);
  bucket_hist_kernel<<<NBLK1, 256, 0, stream>>>(ei + etot, M, etot, chunk, nb1);
  bucket_scan_kernel<<<1, 256, 0, stream>>>(M, bucket_base, NBLK1, nb1, etot);
  bucket_scatter_kernel<<<NBLK1, 256, 0, stream>>>(ei, ei + etot, M, bucketed, etot, chunk, nb1);
  csr_build_kernel<<<nb1, 1024, DCAP * sizeof(unsigned int), stream>>>(
      bucketed, bucket_base, offsets, counts, n);
  edge_attn_kernel<<<(n + 3) / 4, 256, 0, stream>>>(
      (const int*)bucketed, offsets, counts, qbuf, skipbuf, kvbuf, Wout, bout, (float*)d_out, n);
}

// Round 4
// 410.117 us; speedup vs baseline: 2.2688x; 1.9050x over previous
//
#include <hip/hip_runtime.h>
#include <stdint.h>

// ---------------------------------------------------------------------------
// UnimpNet: h = x + mask*emb[y]; q/k/v/skip = h@W*+b; per-edge softmax attn
// (scatter over dst); out = (agg + skip) @ Wout + bout.
// N=100000, E=3200000, F=256, HEADS=2, C=8 (HC=16), NUM_CLASSES=40.
//
// R4 = R3 with the kvbuf pointer-type fix (ushort* -> uint* cast at launch).
// ---------------------------------------------------------------------------

constexpr int F_DIM = 256;
constexpr int NC = 40;
constexpr float RSQRT8 = 0.35355339059327373f;

constexpr int SHIFT = 9;            // nodes per bucket = 512
constexpr int NPBKT = 1 << SHIFT;
constexpr int NBLK1 = 512;          // blocks for hist/scatter passes
constexpr int MAXB1 = 256;          // max buckets
constexpr int DCAP = 32768;         // per-bucket LDS edge staging cap (128KB)

typedef __attribute__((ext_vector_type(8))) short short8;
typedef __attribute__((ext_vector_type(4))) float f32x4;

__device__ __forceinline__ unsigned int bfbits(float f) {
  unsigned int u = __float_as_uint(f);
  return (u + 0x7fffu + ((u >> 16) & 1u)) >> 16;   // RNE f32->bf16 bits
}
__device__ __forceinline__ float bflo(unsigned int u) { return __uint_as_float(u << 16); }
__device__ __forceinline__ float bfhi(unsigned int u) { return __uint_as_float(u & 0xffff0000u); }

// --------------------------- mask layout detect ----------------------------
__global__ void detect_mask_kernel(const unsigned char* __restrict__ m, int* __restrict__ flag) {
  __shared__ int any;
  if (threadIdx.x == 0) any = 0;
  __syncthreads();
  int acc = 0;
  for (int i = threadIdx.x; i < 1024; i += blockDim.x)
    acc |= m[i * 4 + 1] | m[i * 4 + 2] | m[i * 4 + 3];
  if (acc) atomicOr(&any, 1);
  __syncthreads();
  if (threadIdx.x == 0) *flag = any ? 0 : 1;   // 1 == int32 layout
}

// ------------------- weight prep: [64 cols][256 k] bf16 --------------------
// cols 0-15=q, 16-31=k, 32-47=v, 48-63=skip. wbf[col*256+k] = W[k][col&15].
__global__ void weight_prep_kernel(const float* __restrict__ Wq, const float* __restrict__ Wk,
                                   const float* __restrict__ Wv, const float* __restrict__ Ws,
                                   ushort* __restrict__ wbf) {
  int i = blockIdx.x * 256 + threadIdx.x;
  if (i >= 64 * 256) return;
  int col = i >> 8, k = i & 255;
  const float* W = (col < 16) ? Wq : (col < 32) ? Wk : (col < 48) ? Wv : Ws;
  wbf[i] = (ushort)bfbits(W[k * 16 + (col & 15)]);
}

// --------------------- fused maskemb + 4 GEMMs via MFMA --------------------
// 64 nodes/block, 4 waves x 16 rows. A (=h rows) loaded from global per lane
// (row = lane&15, k-slot group = lane>>4), emb-add fused, cvt to bf16.
// B from LDS (staged once). 8 k-steps of mfma_f32_16x16x32_bf16 x 4 col-tiles.
__global__ __launch_bounds__(256) void fused_gemm_mfma(
    const float* __restrict__ x, const int* __restrict__ y,
    const unsigned char* __restrict__ maskraw, const int* __restrict__ flag,
    const float* __restrict__ emb, const ushort* __restrict__ wbf,
    const float* __restrict__ bq, const float* __restrict__ bk,
    const float* __restrict__ bv, const float* __restrict__ bs,
    float* __restrict__ qout, float* __restrict__ skipout,
    ushort* __restrict__ kvout, int n)
{
  __shared__ ushort wlds[64][272];   // pad 256->272: 16B-aligned rows
  const int tid = threadIdx.x;

  {  // stage weights: 2048 x 16B segments
    const uint4* wsrc = (const uint4*)wbf;
    for (int i = tid; i < 2048; i += 256) {
      int col = i >> 5, seg = i & 31;
      uint4 d = wsrc[i];
      *(uint4*)&wlds[col][seg * 8] = d;
    }
  }
  __syncthreads();

  const int w = tid >> 6, lane = tid & 63;
  const int r15 = lane & 15, grp = lane >> 4;
  const int nbase = blockIdx.x * 64 + w * 16;
  int row = min(nbase + r15, n - 1);
  const int flg = *flag;
  bool msk = flg ? (((const int*)maskraw)[row] != 0) : (maskraw[row] != 0);
  int cls = y[row];

  f32x4 acc[4];
#pragma unroll
  for (int ct = 0; ct < 4; ++ct)
#pragma unroll
    for (int j = 0; j < 4; ++j) acc[ct][j] = 0.f;

  const float4* xp = (const float4*)(x + (size_t)row * F_DIM + grp * 8);
  const float4* ep = (const float4*)(emb + (size_t)cls * F_DIM + grp * 8);

  for (int ks = 0; ks < 8; ++ks) {
    float4 xa = xp[ks * 8];
    float4 xb = xp[ks * 8 + 1];
    if (msk) {
      float4 ea = ep[ks * 8], eb = ep[ks * 8 + 1];
      xa.x += ea.x; xa.y += ea.y; xa.z += ea.z; xa.w += ea.w;
      xb.x += eb.x; xb.y += eb.y; xb.z += eb.z; xb.w += eb.w;
    }
    short8 a;
    a[0] = (short)bfbits(xa.x); a[1] = (short)bfbits(xa.y);
    a[2] = (short)bfbits(xa.z); a[3] = (short)bfbits(xa.w);
    a[4] = (short)bfbits(xb.x); a[5] = (short)bfbits(xb.y);
    a[6] = (short)bfbits(xb.z); a[7] = (short)bfbits(xb.w);
    const int kofs = ks * 32 + grp * 8;
#pragma unroll
    for (int ct = 0; ct < 4; ++ct) {
      short8 b = *(const short8*)&wlds[ct * 16 + r15][kofs];
      acc[ct] = __builtin_amdgcn_mfma_f32_16x16x32_bf16(a, b, acc[ct], 0, 0, 0);
    }
  }

  // D layout (HW-verified): col = lane&15, row = (lane>>4)*4 + reg
  const float bqv = bq[r15], bkv = bk[r15], bvv = bv[r15], bsv = bs[r15];
#pragma unroll
  for (int r = 0; r < 4; ++r) {
    int nr = nbase + grp * 4 + r;
    if (nr < n) {
      qout[(size_t)nr * 16 + r15] = (acc[0][r] + bqv) * RSQRT8;
      kvout[(size_t)nr * 32 + r15] = (ushort)bfbits(acc[1][r] + bkv);
      kvout[(size_t)nr * 32 + 16 + r15] = (ushort)bfbits(acc[2][r] + bvv);
      skipout[(size_t)nr * 16 + r15] = acc[3][r] + bsv;
    }
  }
}

// ------------------ A) per-block bucket histogram (LDS only) ---------------
// M layout: [bucket][block]  (transposed for coalesced column scans)
__global__ __launch_bounds__(256) void bucket_hist_kernel(
    const int* __restrict__ dstA, int* __restrict__ M, int etot, int chunk, int nb1)
{
  __shared__ int h[MAXB1];
  const int tid = threadIdx.x, b = blockIdx.x;
  for (int i = tid; i < nb1; i += 256) h[i] = 0;
  __syncthreads();
  int s = b * chunk, e = min(etot, s + chunk);
  for (int i = s + tid; i < e; i += 256) atomicAdd(&h[dstA[i] >> SHIFT], 1);
  __syncthreads();
  for (int i = tid; i < nb1; i += 256) M[i * NBLK1 + b] = h[i];
}

// ------------- B1) per-bucket scan over blocks (parallel) ------------------
__global__ __launch_bounds__(NBLK1) void col_scan_kernel(
    int* __restrict__ M, int* __restrict__ tot)
{
  __shared__ int s[NBLK1];
  const int t = threadIdx.x, k = blockIdx.x;
  int v = M[k * NBLK1 + t];
  s[t] = v;
  __syncthreads();
  for (int off = 1; off < NBLK1; off <<= 1) {
    int tt = (t >= off) ? s[t - off] : 0;
    __syncthreads();
    s[t] += tt;
    __syncthreads();
  }
  M[k * NBLK1 + t] = s[t] - v;          // exclusive within bucket
  if (t == NBLK1 - 1) tot[k] = s[t];
}

// ------------- B2) scan bucket totals -> bucket_base -----------------------
__global__ __launch_bounds__(256) void tot_scan_kernel(
    const int* __restrict__ tot, int* __restrict__ bucket_base, int nb1, int etot)
{
  __shared__ int s[256];
  const int t = threadIdx.x;
  int v = (t < nb1) ? tot[t] : 0;
  s[t] = v;
  __syncthreads();
  for (int off = 1; off < 256; off <<= 1) {
    int tt = (t >= off) ? s[t - off] : 0;
    __syncthreads();
    s[t] += tt;
    __syncthreads();
  }
  if (t < nb1) bucket_base[t] = s[t] - v;
  if (t == 0) bucket_base[nb1] = etot;
}

// ------------------ C) scatter packed edges into bucket regions ------------
__global__ __launch_bounds__(256) void bucket_scatter_kernel(
    const int* __restrict__ srcA, const int* __restrict__ dstA,
    const int* __restrict__ M, const int* __restrict__ bucket_base,
    unsigned int* __restrict__ bucketed, int etot, int chunk, int nb1)
{
  __shared__ int c[MAXB1];
  const int tid = threadIdx.x, b = blockIdx.x;
  for (int i = tid; i < nb1; i += 256) c[i] = M[i * NBLK1 + b] + bucket_base[i];
  __syncthreads();
  int s = b * chunk, e = min(etot, s + chunk);
  for (int i = s + tid; i < e; i += 256) {
    int d = dstA[i];
    int k = d >> SHIFT;
    int pos = atomicAdd(&c[k], 1);
    bucketed[pos] = ((unsigned)(d & (NPBKT - 1)) << 17) | (unsigned)srcA[i];
  }
}

// ------------- D) per-bucket CSR: stage in LDS, hist, scan, scatter --------
__global__ __launch_bounds__(1024) void csr_build_kernel(
    unsigned int* __restrict__ bucketed, const int* __restrict__ bucket_base,
    int* __restrict__ offsets, int* __restrict__ counts, int n)
{
  extern __shared__ unsigned int sedge[];          // DCAP entries
  __shared__ int h[NPBKT], sc[NPBKT], cur[NPBKT];
  const int tid = threadIdx.x, k = blockIdx.x;
  const int base = bucket_base[k];
  int cnt = bucket_base[k + 1] - base;
  if (cnt > DCAP) cnt = DCAP;
  if (tid < NPBKT) h[tid] = 0;
  __syncthreads();
  for (int i = tid; i < cnt; i += 1024) {
    unsigned p = bucketed[base + i];
    sedge[i] = p;
    atomicAdd(&h[p >> 17], 1);
  }
  __syncthreads();
  int v = (tid < NPBKT) ? h[tid] : 0;
  if (tid < NPBKT) sc[tid] = v;
  __syncthreads();
  for (int off = 1; off < NPBKT; off <<= 1) {
    int t = 0;
    if (tid < NPBKT && tid >= off) t = sc[tid - off];
    __syncthreads();
    if (tid < NPBKT) sc[tid] += t;
    __syncthreads();
  }
  if (tid < NPBKT) {
    int excl = sc[tid] - v;
    cur[tid] = excl;
    int node = (k << SHIFT) + tid;
    if (node < n) { offsets[node] = base + excl; counts[node] = v; }
  }
  __syncthreads();
  for (int i = tid; i < cnt; i += 1024) {
    unsigned p = sedge[i];
    int pos = atomicAdd(&cur[p >> 17], 1);
    bucketed[base + pos] = p & 0x1FFFFu;
  }
}

// ------------- per-dst attention softmax + agg + classifier ----------------
__global__ __launch_bounds__(256) void edge_attn_kernel(
    const int* __restrict__ csr, const int* __restrict__ offsets,
    const int* __restrict__ counts, const float* __restrict__ q,
    const float* __restrict__ skip, const unsigned int* __restrict__ kv,
    const float* __restrict__ Wout, const float* __restrict__ bout,
    float* __restrict__ out, int n)
{
  int wave = (blockIdx.x * blockDim.x + threadIdx.x) >> 6;
  int lane = threadIdx.x & 63;
  if (wave >= n) return;
  int dst = __builtin_amdgcn_readfirstlane(wave);

  int start = offsets[dst];
  int cnt = counts[dst];

  float qv[16];
#pragma unroll
  for (int o = 0; o < 16; ++o) qv[o] = q[(size_t)dst * 16 + o];

  float es0 = 0.f, es1 = 0.f;
  float acc[16];
#pragma unroll
  for (int o = 0; o < 16; ++o) acc[o] = 0.f;

  for (int b = 0; b < cnt; b += 64) {
    int e = b + lane;
    if (e < cnt) {
      int s = csr[start + e];
      const uint4* kvp = (const uint4*)(kv + (size_t)s * 16);
      uint4 kA = kvp[0], kB = kvp[1], vA = kvp[2], vB = kvp[3];
      float kf[16], vf[16];
      kf[0] = bflo(kA.x); kf[1] = bfhi(kA.x); kf[2] = bflo(kA.y); kf[3] = bfhi(kA.y);
      kf[4] = bflo(kA.z); kf[5] = bfhi(kA.z); kf[6] = bflo(kA.w); kf[7] = bfhi(kA.w);
      kf[8] = bflo(kB.x); kf[9] = bfhi(kB.x); kf[10] = bflo(kB.y); kf[11] = bfhi(kB.y);
      kf[12] = bflo(kB.z); kf[13] = bfhi(kB.z); kf[14] = bflo(kB.w); kf[15] = bfhi(kB.w);
      vf[0] = bflo(vA.x); vf[1] = bfhi(vA.x); vf[2] = bflo(vA.y); vf[3] = bfhi(vA.y);
      vf[4] = bflo(vA.z); vf[5] = bfhi(vA.z); vf[6] = bflo(vA.w); vf[7] = bfhi(vA.w);
      vf[8] = bflo(vB.x); vf[9] = bfhi(vB.x); vf[10] = bflo(vB.y); vf[11] = bfhi(vB.y);
      vf[12] = bflo(vB.z); vf[13] = bfhi(vB.z); vf[14] = bflo(vB.w); vf[15] = bfhi(vB.w);
      float a0 = 0.f, a1 = 0.f;
#pragma unroll
      for (int c2 = 0; c2 < 8; ++c2) {
        a0 = fmaf(qv[c2], kf[c2], a0);
        a1 = fmaf(qv[8 + c2], kf[8 + c2], a1);
      }
      float e0 = __expf(a0), e1 = __expf(a1);
      es0 += e0; es1 += e1;
#pragma unroll
      for (int c2 = 0; c2 < 8; ++c2) {
        acc[c2] = fmaf(e0, vf[c2], acc[c2]);
        acc[8 + c2] = fmaf(e1, vf[8 + c2], acc[8 + c2]);
      }
    }
  }

#pragma unroll
  for (int m = 1; m <= 32; m <<= 1) {
    es0 += __shfl_xor(es0, m, 64);
    es1 += __shfl_xor(es1, m, 64);
#pragma unroll
    for (int o = 0; o < 16; ++o) acc[o] += __shfl_xor(acc[o], m, 64);
  }

  float d0 = es0 + 1e-16f, d1 = es1 + 1e-16f;
  float out16[16];
#pragma unroll
  for (int o = 0; o < 8; ++o)  out16[o] = acc[o] / d0 + skip[(size_t)dst * 16 + o];
#pragma unroll
  for (int o = 8; o < 16; ++o) out16[o] = acc[o] / d1 + skip[(size_t)dst * 16 + o];

  if (lane < NC) {
    float r = bout[lane];
#pragma unroll
    for (int c2 = 0; c2 < 16; ++c2) r = fmaf(out16[c2], Wout[c2 * NC + lane], r);
    out[(size_t)dst * NC + lane] = r;
  }
}

// ---------------------------------------------------------------------------
extern "C" void kernel_launch(void* const* d_in, const int* in_sizes, int n_in,
                              void* d_out, int out_size, void* d_ws, size_t ws_size,
                              hipStream_t stream) {
  const float* x = (const float*)d_in[0];
  const int* y = (const int*)d_in[1];
  const int* ei = (const int*)d_in[2];
  const unsigned char* mask = (const unsigned char*)d_in[3];
  const float* emb = (const float*)d_in[4];
  const float* Wq = (const float*)d_in[5];
  const float* bq = (const float*)d_in[6];
  const float* Wk = (const float*)d_in[7];
  const float* bk = (const float*)d_in[8];
  const float* Wv = (const float*)d_in[9];
  const float* bv = (const float*)d_in[10];
  const float* Ws = (const float*)d_in[11];
  const float* bs = (const float*)d_in[12];
  const float* Wout = (const float*)d_in[13];
  const float* bout = (const float*)d_in[14];

  const int n = in_sizes[1];          // 100000
  const int etot = in_sizes[2] / 2;   // 3200000
  const int nb1 = (n + NPBKT - 1) >> SHIFT;          // 196 buckets
  const int chunk = (etot + NBLK1 - 1) / NBLK1;      // edges per block

  char* w = (char*)d_ws;
  size_t off = 0;
  auto alloc = [&](size_t bytes) -> void* {
    off = (off + 255) & ~(size_t)255;
    void* p = w + off;
    off += bytes;
    return p;
  };
  int* flag = (int*)alloc(sizeof(int));
  ushort* wbf = (ushort*)alloc((size_t)64 * 256 * sizeof(ushort));
  float* qbuf = (float*)alloc((size_t)n * 16 * sizeof(float));
  float* skipbuf = (float*)alloc((size_t)n * 16 * sizeof(float));
  ushort* kvbuf = (ushort*)alloc((size_t)n * 32 * sizeof(ushort));
  int* counts = (int*)alloc((size_t)n * sizeof(int));
  int* offsets = (int*)alloc((size_t)n * sizeof(int));
  int* M = (int*)alloc((size_t)MAXB1 * NBLK1 * sizeof(int));
  int* tot = (int*)alloc((size_t)MAXB1 * sizeof(int));
  int* bucket_base = (int*)alloc(((size_t)nb1 + 1) * sizeof(int));
  unsigned int* bucketed = (unsigned int*)alloc((size_t)etot * sizeof(unsigned int));

  detect_mask_kernel<<<1, 256, 0, stream>>>(mask, flag);
  weight_prep_kernel<<<64, 256, 0, stream>>>(Wq, Wk, Wv, Ws, wbf);
  fused_gemm_mfma<<<(n + 63) / 64, 256, 0, stream>>>(
      x, y, mask, flag, emb, wbf, bq, bk, bv, bs, qbuf, skipbuf, kvbuf, n);
  bucket_hist_kernel<<<NBLK1, 256, 0, stream>>>(ei + etot, M, etot, chunk, nb1);
  col_scan_kernel<<<nb1, NBLK1, 0, stream>>>(M, tot);
  tot_scan_kernel<<<1, 256, 0, stream>>>(tot, bucket_base, nb1, etot);
  bucket_scatter_kernel<<<NBLK1, 256, 0, stream>>>(ei, ei + etot, M, bucket_base, bucketed, etot, chunk, nb1);
  csr_build_kernel<<<nb1, 1024, DCAP * sizeof(unsigned int), stream>>>(
      bucketed, bucket_base, offsets, counts, n);
  edge_attn_kernel<<<(n + 3) / 4, 256, 0, stream>>>(
      (const int*)bucketed, offsets, counts, qbuf, skipbuf,
      (const unsigned int*)kvbuf, Wout, bout, (float*)d_out, n);
}

// Round 5
// 338.259 us; speedup vs baseline: 2.7508x; 1.2124x over previous
//
#include <hip/hip_runtime.h>
#include <stdint.h>

// ---------------------------------------------------------------------------
// UnimpNet: h = x + mask*emb[y]; q/k/v/skip = h@W*+b; per-edge softmax attn
// (scatter over dst); out = (agg + skip) @ Wout + bout.
// N=100000, E=3200000, F=256, HEADS=2, C=8 (HC=16), NUM_CLASSES=40.
//
// R5: edge_attn -> 16 lanes per dst (4 dst/wave): 6x less shuffle-reduce,
// better lane utilization at avg degree 32.
// ---------------------------------------------------------------------------

constexpr int F_DIM = 256;
constexpr int NC = 40;
constexpr float RSQRT8 = 0.35355339059327373f;

constexpr int SHIFT = 9;            // nodes per bucket = 512
constexpr int NPBKT = 1 << SHIFT;
constexpr int NBLK1 = 512;          // blocks for hist/scatter passes
constexpr int MAXB1 = 256;          // max buckets
constexpr int DCAP = 32768;         // per-bucket LDS edge staging cap (128KB)

typedef __attribute__((ext_vector_type(8))) short short8;
typedef __attribute__((ext_vector_type(4))) float f32x4;

__device__ __forceinline__ unsigned int bfbits(float f) {
  unsigned int u = __float_as_uint(f);
  return (u + 0x7fffu + ((u >> 16) & 1u)) >> 16;   // RNE f32->bf16 bits
}
__device__ __forceinline__ float bflo(unsigned int u) { return __uint_as_float(u << 16); }
__device__ __forceinline__ float bfhi(unsigned int u) { return __uint_as_float(u & 0xffff0000u); }

// --------------------------- mask layout detect ----------------------------
__global__ void detect_mask_kernel(const unsigned char* __restrict__ m, int* __restrict__ flag) {
  __shared__ int any;
  if (threadIdx.x == 0) any = 0;
  __syncthreads();
  int acc = 0;
  for (int i = threadIdx.x; i < 1024; i += blockDim.x)
    acc |= m[i * 4 + 1] | m[i * 4 + 2] | m[i * 4 + 3];
  if (acc) atomicOr(&any, 1);
  __syncthreads();
  if (threadIdx.x == 0) *flag = any ? 0 : 1;   // 1 == int32 layout
}

// ------------------- weight prep: [64 cols][256 k] bf16 --------------------
__global__ void weight_prep_kernel(const float* __restrict__ Wq, const float* __restrict__ Wk,
                                   const float* __restrict__ Wv, const float* __restrict__ Ws,
                                   ushort* __restrict__ wbf) {
  int i = blockIdx.x * 256 + threadIdx.x;
  if (i >= 64 * 256) return;
  int col = i >> 8, k = i & 255;
  const float* W = (col < 16) ? Wq : (col < 32) ? Wk : (col < 48) ? Wv : Ws;
  wbf[i] = (ushort)bfbits(W[k * 16 + (col & 15)]);
}

// --------------------- fused maskemb + 4 GEMMs via MFMA --------------------
__global__ __launch_bounds__(256) void fused_gemm_mfma(
    const float* __restrict__ x, const int* __restrict__ y,
    const unsigned char* __restrict__ maskraw, const int* __restrict__ flag,
    const float* __restrict__ emb, const ushort* __restrict__ wbf,
    const float* __restrict__ bq, const float* __restrict__ bk,
    const float* __restrict__ bv, const float* __restrict__ bs,
    float* __restrict__ qout, float* __restrict__ skipout,
    ushort* __restrict__ kvout, int n)
{
  __shared__ ushort wlds[64][272];   // pad 256->272: 16B-aligned rows
  const int tid = threadIdx.x;

  {  // stage weights: 2048 x 16B segments
    const uint4* wsrc = (const uint4*)wbf;
    for (int i = tid; i < 2048; i += 256) {
      int col = i >> 5, seg = i & 31;
      uint4 d = wsrc[i];
      *(uint4*)&wlds[col][seg * 8] = d;
    }
  }
  __syncthreads();

  const int w = tid >> 6, lane = tid & 63;
  const int r15 = lane & 15, grp = lane >> 4;
  const int nbase = blockIdx.x * 64 + w * 16;
  int row = min(nbase + r15, n - 1);
  const int flg = *flag;
  bool msk = flg ? (((const int*)maskraw)[row] != 0) : (maskraw[row] != 0);
  int cls = y[row];

  f32x4 acc[4];
#pragma unroll
  for (int ct = 0; ct < 4; ++ct)
#pragma unroll
    for (int j = 0; j < 4; ++j) acc[ct][j] = 0.f;

  const float4* xp = (const float4*)(x + (size_t)row * F_DIM + grp * 8);
  const float4* ep = (const float4*)(emb + (size_t)cls * F_DIM + grp * 8);

  for (int ks = 0; ks < 8; ++ks) {
    float4 xa = xp[ks * 8];
    float4 xb = xp[ks * 8 + 1];
    if (msk) {
      float4 ea = ep[ks * 8], eb = ep[ks * 8 + 1];
      xa.x += ea.x; xa.y += ea.y; xa.z += ea.z; xa.w += ea.w;
      xb.x += eb.x; xb.y += eb.y; xb.z += eb.z; xb.w += eb.w;
    }
    short8 a;
    a[0] = (short)bfbits(xa.x); a[1] = (short)bfbits(xa.y);
    a[2] = (short)bfbits(xa.z); a[3] = (short)bfbits(xa.w);
    a[4] = (short)bfbits(xb.x); a[5] = (short)bfbits(xb.y);
    a[6] = (short)bfbits(xb.z); a[7] = (short)bfbits(xb.w);
    const int kofs = ks * 32 + grp * 8;
#pragma unroll
    for (int ct = 0; ct < 4; ++ct) {
      short8 b = *(const short8*)&wlds[ct * 16 + r15][kofs];
      acc[ct] = __builtin_amdgcn_mfma_f32_16x16x32_bf16(a, b, acc[ct], 0, 0, 0);
    }
  }

  // D layout (HW-verified): col = lane&15, row = (lane>>4)*4 + reg
  const float bqv = bq[r15], bkv = bk[r15], bvv = bv[r15], bsv = bs[r15];
#pragma unroll
  for (int r = 0; r < 4; ++r) {
    int nr = nbase + grp * 4 + r;
    if (nr < n) {
      qout[(size_t)nr * 16 + r15] = (acc[0][r] + bqv) * RSQRT8;
      kvout[(size_t)nr * 32 + r15] = (ushort)bfbits(acc[1][r] + bkv);
      kvout[(size_t)nr * 32 + 16 + r15] = (ushort)bfbits(acc[2][r] + bvv);
      skipout[(size_t)nr * 16 + r15] = acc[3][r] + bsv;
    }
  }
}

// ------------------ A) per-block bucket histogram (LDS only) ---------------
__global__ __launch_bounds__(256) void bucket_hist_kernel(
    const int* __restrict__ dstA, int* __restrict__ M, int etot, int chunk, int nb1)
{
  __shared__ int h[MAXB1];
  const int tid = threadIdx.x, b = blockIdx.x;
  for (int i = tid; i < nb1; i += 256) h[i] = 0;
  __syncthreads();
  int s = b * chunk, e = min(etot, s + chunk);
  for (int i = s + tid; i < e; i += 256) atomicAdd(&h[dstA[i] >> SHIFT], 1);
  __syncthreads();
  for (int i = tid; i < nb1; i += 256) M[i * NBLK1 + b] = h[i];
}

// ------------- B1) per-bucket scan over blocks (parallel) ------------------
__global__ __launch_bounds__(NBLK1) void col_scan_kernel(
    int* __restrict__ M, int* __restrict__ tot)
{
  __shared__ int s[NBLK1];
  const int t = threadIdx.x, k = blockIdx.x;
  int v = M[k * NBLK1 + t];
  s[t] = v;
  __syncthreads();
  for (int off = 1; off < NBLK1; off <<= 1) {
    int tt = (t >= off) ? s[t - off] : 0;
    __syncthreads();
    s[t] += tt;
    __syncthreads();
  }
  M[k * NBLK1 + t] = s[t] - v;          // exclusive within bucket
  if (t == NBLK1 - 1) tot[k] = s[t];
}

// ------------- B2) scan bucket totals -> bucket_base -----------------------
__global__ __launch_bounds__(256) void tot_scan_kernel(
    const int* __restrict__ tot, int* __restrict__ bucket_base, int nb1, int etot)
{
  __shared__ int s[256];
  const int t = threadIdx.x;
  int v = (t < nb1) ? tot[t] : 0;
  s[t] = v;
  __syncthreads();
  for (int off = 1; off < 256; off <<= 1) {
    int tt = (t >= off) ? s[t - off] : 0;
    __syncthreads();
    s[t] += tt;
    __syncthreads();
  }
  if (t < nb1) bucket_base[t] = s[t] - v;
  if (t == 0) bucket_base[nb1] = etot;
}

// ------------------ C) scatter packed edges into bucket regions ------------
__global__ __launch_bounds__(256) void bucket_scatter_kernel(
    const int* __restrict__ srcA, const int* __restrict__ dstA,
    const int* __restrict__ M, const int* __restrict__ bucket_base,
    unsigned int* __restrict__ bucketed, int etot, int chunk, int nb1)
{
  __shared__ int c[MAXB1];
  const int tid = threadIdx.x, b = blockIdx.x;
  for (int i = tid; i < nb1; i += 256) c[i] = M[i * NBLK1 + b] + bucket_base[i];
  __syncthreads();
  int s = b * chunk, e = min(etot, s + chunk);
  for (int i = s + tid; i < e; i += 256) {
    int d = dstA[i];
    int k = d >> SHIFT;
    int pos = atomicAdd(&c[k], 1);
    bucketed[pos] = ((unsigned)(d & (NPBKT - 1)) << 17) | (unsigned)srcA[i];
  }
}

// ------------- D) per-bucket CSR: stage in LDS, hist, scan, scatter --------
__global__ __launch_bounds__(1024) void csr_build_kernel(
    unsigned int* __restrict__ bucketed, const int* __restrict__ bucket_base,
    int* __restrict__ offsets, int* __restrict__ counts, int n)
{
  extern __shared__ unsigned int sedge[];          // DCAP entries
  __shared__ int h[NPBKT], sc[NPBKT], cur[NPBKT];
  const int tid = threadIdx.x, k = blockIdx.x;
  const int base = bucket_base[k];
  int cnt = bucket_base[k + 1] - base;
  if (cnt > DCAP) cnt = DCAP;
  if (tid < NPBKT) h[tid] = 0;
  __syncthreads();
  for (int i = tid; i < cnt; i += 1024) {
    unsigned p = bucketed[base + i];
    sedge[i] = p;
    atomicAdd(&h[p >> 17], 1);
  }
  __syncthreads();
  int v = (tid < NPBKT) ? h[tid] : 0;
  if (tid < NPBKT) sc[tid] = v;
  __syncthreads();
  for (int off = 1; off < NPBKT; off <<= 1) {
    int t = 0;
    if (tid < NPBKT && tid >= off) t = sc[tid - off];
    __syncthreads();
    if (tid < NPBKT) sc[tid] += t;
    __syncthreads();
  }
  if (tid < NPBKT) {
    int excl = sc[tid] - v;
    cur[tid] = excl;
    int node = (k << SHIFT) + tid;
    if (node < n) { offsets[node] = base + excl; counts[node] = v; }
  }
  __syncthreads();
  for (int i = tid; i < cnt; i += 1024) {
    unsigned p = sedge[i];
    int pos = atomicAdd(&cur[p >> 17], 1);
    bucketed[base + pos] = p & 0x1FFFFu;
  }
}

// ------------- per-dst attention softmax + agg + classifier ----------------
// 16 lanes per dst, 4 dsts per wave. Butterfly reduce over 4 steps (xor
// masks 1,2,4,8 stay within the 16-lane group). Classifier: lane j emits
// classes j, j+16, and j+32 (j<8).
__global__ __launch_bounds__(256) void edge_attn_kernel(
    const int* __restrict__ csr, const int* __restrict__ offsets,
    const int* __restrict__ counts, const float* __restrict__ q,
    const float* __restrict__ skip, const unsigned int* __restrict__ kv,
    const float* __restrict__ Wout, const float* __restrict__ bout,
    float* __restrict__ out, int n)
{
  const int dst = (blockIdx.x * blockDim.x + threadIdx.x) >> 4;
  const int l16 = threadIdx.x & 15;
  if (dst >= n) return;

  const int start = offsets[dst];
  const int cnt = counts[dst];

  float qv[16];
  {
    const float4* qp = (const float4*)(q + (size_t)dst * 16);
    float4 q0 = qp[0], q1 = qp[1], q2 = qp[2], q3 = qp[3];
    qv[0] = q0.x; qv[1] = q0.y; qv[2] = q0.z; qv[3] = q0.w;
    qv[4] = q1.x; qv[5] = q1.y; qv[6] = q1.z; qv[7] = q1.w;
    qv[8] = q2.x; qv[9] = q2.y; qv[10] = q2.z; qv[11] = q2.w;
    qv[12] = q3.x; qv[13] = q3.y; qv[14] = q3.z; qv[15] = q3.w;
  }

  float es0 = 0.f, es1 = 0.f;
  float acc[16];
#pragma unroll
  for (int o = 0; o < 16; ++o) acc[o] = 0.f;

  for (int e = l16; e < cnt; e += 16) {
    int s = csr[start + e];
    const uint4* kvp = (const uint4*)(kv + (size_t)s * 16);
    uint4 kA = kvp[0], kB = kvp[1], vA = kvp[2], vB = kvp[3];
    float kf[16], vf[16];
    kf[0] = bflo(kA.x); kf[1] = bfhi(kA.x); kf[2] = bflo(kA.y); kf[3] = bfhi(kA.y);
    kf[4] = bflo(kA.z); kf[5] = bfhi(kA.z); kf[6] = bflo(kA.w); kf[7] = bfhi(kA.w);
    kf[8] = bflo(kB.x); kf[9] = bfhi(kB.x); kf[10] = bflo(kB.y); kf[11] = bfhi(kB.y);
    kf[12] = bflo(kB.z); kf[13] = bfhi(kB.z); kf[14] = bflo(kB.w); kf[15] = bfhi(kB.w);
    vf[0] = bflo(vA.x); vf[1] = bfhi(vA.x); vf[2] = bflo(vA.y); vf[3] = bfhi(vA.y);
    vf[4] = bflo(vA.z); vf[5] = bfhi(vA.z); vf[6] = bflo(vA.w); vf[7] = bfhi(vA.w);
    vf[8] = bflo(vB.x); vf[9] = bfhi(vB.x); vf[10] = bflo(vB.y); vf[11] = bfhi(vB.y);
    vf[12] = bflo(vB.z); vf[13] = bfhi(vB.z); vf[14] = bflo(vB.w); vf[15] = bfhi(vB.w);
    float a0 = 0.f, a1 = 0.f;
#pragma unroll
    for (int c2 = 0; c2 < 8; ++c2) {
      a0 = fmaf(qv[c2], kf[c2], a0);
      a1 = fmaf(qv[8 + c2], kf[8 + c2], a1);
    }
    float e0 = __expf(a0), e1 = __expf(a1);
    es0 += e0; es1 += e1;
#pragma unroll
    for (int c2 = 0; c2 < 8; ++c2) {
      acc[c2] = fmaf(e0, vf[c2], acc[c2]);
      acc[8 + c2] = fmaf(e1, vf[8 + c2], acc[8 + c2]);
    }
  }

#pragma unroll
  for (int m = 1; m <= 8; m <<= 1) {
    es0 += __shfl_xor(es0, m, 64);
    es1 += __shfl_xor(es1, m, 64);
#pragma unroll
    for (int o = 0; o < 16; ++o) acc[o] += __shfl_xor(acc[o], m, 64);
  }

  const float i0 = 1.0f / (es0 + 1e-16f);
  const float i1 = 1.0f / (es1 + 1e-16f);
  float out16[16];
  {
    const float4* sp = (const float4*)(skip + (size_t)dst * 16);
    float4 s0 = sp[0], s1 = sp[1], s2 = sp[2], s3 = sp[3];
    out16[0] = fmaf(acc[0], i0, s0.x);  out16[1] = fmaf(acc[1], i0, s0.y);
    out16[2] = fmaf(acc[2], i0, s0.z);  out16[3] = fmaf(acc[3], i0, s0.w);
    out16[4] = fmaf(acc[4], i0, s1.x);  out16[5] = fmaf(acc[5], i0, s1.y);
    out16[6] = fmaf(acc[6], i0, s1.z);  out16[7] = fmaf(acc[7], i0, s1.w);
    out16[8] = fmaf(acc[8], i1, s2.x);  out16[9] = fmaf(acc[9], i1, s2.y);
    out16[10] = fmaf(acc[10], i1, s2.z); out16[11] = fmaf(acc[11], i1, s2.w);
    out16[12] = fmaf(acc[12], i1, s3.x); out16[13] = fmaf(acc[13], i1, s3.y);
    out16[14] = fmaf(acc[14], i1, s3.z); out16[15] = fmaf(acc[15], i1, s3.w);
  }

  float r0 = bout[l16], r1 = bout[l16 + 16];
#pragma unroll
  for (int c2 = 0; c2 < 16; ++c2) {
    r0 = fmaf(out16[c2], Wout[c2 * NC + l16], r0);
    r1 = fmaf(out16[c2], Wout[c2 * NC + l16 + 16], r1);
  }
  out[(size_t)dst * NC + l16] = r0;
  out[(size_t)dst * NC + l16 + 16] = r1;
  if (l16 < 8) {
    float r2 = bout[l16 + 32];
#pragma unroll
    for (int c2 = 0; c2 < 16; ++c2) r2 = fmaf(out16[c2], Wout[c2 * NC + l16 + 32], r2);
    out[(size_t)dst * NC + l16 + 32] = r2;
  }
}

// ---------------------------------------------------------------------------
extern "C" void kernel_launch(void* const* d_in, const int* in_sizes, int n_in,
                              void* d_out, int out_size, void* d_ws, size_t ws_size,
                              hipStream_t stream) {
  const float* x = (const float*)d_in[0];
  const int* y = (const int*)d_in[1];
  const int* ei = (const int*)d_in[2];
  const unsigned char* mask = (const unsigned char*)d_in[3];
  const float* emb = (const float*)d_in[4];
  const float* Wq = (const float*)d_in[5];
  const float* bq = (const float*)d_in[6];
  const float* Wk = (const float*)d_in[7];
  const float* bk = (const float*)d_in[8];
  const float* Wv = (const float*)d_in[9];
  const float* bv = (const float*)d_in[10];
  const float* Ws = (const float*)d_in[11];
  const float* bs = (const float*)d_in[12];
  const float* Wout = (const float*)d_in[13];
  const float* bout = (const float*)d_in[14];

  const int n = in_sizes[1];          // 100000
  const int etot = in_sizes[2] / 2;   // 3200000
  const int nb1 = (n + NPBKT - 1) >> SHIFT;          // 196 buckets
  const int chunk = (etot + NBLK1 - 1) / NBLK1;      // edges per block

  char* w = (char*)d_ws;
  size_t off = 0;
  auto alloc = [&](size_t bytes) -> void* {
    off = (off + 255) & ~(size_t)255;
    void* p = w + off;
    off += bytes;
    return p;
  };
  int* flag = (int*)alloc(sizeof(int));
  ushort* wbf = (ushort*)alloc((size_t)64 * 256 * sizeof(ushort));
  float* qbuf = (float*)alloc((size_t)n * 16 * sizeof(float));
  float* skipbuf = (float*)alloc((size_t)n * 16 * sizeof(float));
  ushort* kvbuf = (ushort*)alloc((size_t)n * 32 * sizeof(ushort));
  int* counts = (int*)alloc((size_t)n * sizeof(int));
  int* offsets = (int*)alloc((size_t)n * sizeof(int));
  int* M = (int*)alloc((size_t)MAXB1 * NBLK1 * sizeof(int));
  int* tot = (int*)alloc((size_t)MAXB1 * sizeof(int));
  int* bucket_base = (int*)alloc(((size_t)nb1 + 1) * sizeof(int));
  unsigned int* bucketed = (unsigned int*)alloc((size_t)etot * sizeof(unsigned int));

  detect_mask_kernel<<<1, 256, 0, stream>>>(mask, flag);
  weight_prep_kernel<<<64, 256, 0, stream>>>(Wq, Wk, Wv, Ws, wbf);
  fused_gemm_mfma<<<(n + 63) / 64, 256, 0, stream>>>(
      x, y, mask, flag, emb, wbf, bq, bk, bv, bs, qbuf, skipbuf, kvbuf, n);
  bucket_hist_kernel<<<NBLK1, 256, 0, stream>>>(ei + etot, M, etot, chunk, nb1);
  col_scan_kernel<<<nb1, NBLK1, 0, stream>>>(M, tot);
  tot_scan_kernel<<<1, 256, 0, stream>>>(tot, bucket_base, nb1, etot);
  bucket_scatter_kernel<<<NBLK1, 256, 0, stream>>>(ei, ei + etot, M, bucket_base, bucketed, etot, chunk, nb1);
  csr_build_kernel<<<nb1, 1024, DCAP * sizeof(unsigned int), stream>>>(
      bucketed, bucket_base, offsets, counts, n);
  edge_attn_kernel<<<(n + 15) / 16, 256, 0, stream>>>(
      (const int*)bucketed, offsets, counts, qbuf, skipbuf,
      (const unsigned int*)kvbuf, Wout, bout, (float*)d_out, n);
}